// Round 7
// baseline (1012.382 us; speedup 1.0000x reference)
//
#include <hip/hip_runtime.h>
#include <math.h>

// Problem constants
#define B_SZ 512
#define T_SZ 128
#define D_SZ 128
#define H_SZ 256
#define K_SZ 49
#define L_SZ 7
#define E_SZ 512   // 2H

typedef float f32x4 __attribute__((ext_vector_type(4)));
typedef short bf16x8 __attribute__((ext_vector_type(8)));

__device__ __forceinline__ unsigned short f2bf(float f) {
    union { float f; unsigned u; } v; v.f = f;
    unsigned r = v.u + 0x7FFFu + ((v.u >> 16) & 1u);
    return (unsigned short)(r >> 16);
}
__device__ __forceinline__ float bf2f(unsigned short h) {
    union { unsigned u; float f; } v; v.u = ((unsigned)h) << 16;
    return v.f;
}
__device__ __forceinline__ float fsigm(float x) {
    return __fdividef(1.0f, 1.0f + __expf(-x));
}
__device__ __forceinline__ float ftanh(float x) {
    x = fminf(fmaxf(x, -20.0f), 20.0f);
    float e = __expf(2.0f * x);
    return __fdividef(e - 1.0f, e + 1.0f);
}
__device__ __forceinline__ unsigned char f2fp8(float v) {
    int p = __builtin_amdgcn_cvt_pk_fp8_f32(v, 0.f, 0, false);
    return (unsigned char)(p & 0xff);
}

// MFMA with B-operand pinned to AGPR (hard register-class constraint):
// forces the weight value to live in the accumulator file across the loop.
__device__ __forceinline__ void mfma_fp8_a(f32x4& acc, long a, long w) {
    asm volatile("v_mfma_f32_16x16x32_fp8_fp8 %0, %1, %2, %0"
                 : "+v"(acc)
                 : "v"(a), "a"(w));
}

// ---------------------------------------------------------------------------
// Weight prep into fp8 per-wave VGPR-fragment order (8 waves/dir):
// Wt idx = (((dw*12 + kk)*4 + hi)*128 + (f*16+u))*8 + e,  dw = dir*8 + wv
// f = q*4+g ; cell j = wv*32 + q*16 + u ; orig row = g*256 + j
// k = kk*32 + hi*8 + e ; k<256 -> w_hh[row][k] else w_ih[row][k-256]
// bp[dw*128 + f*16+u] = combined bias (fp32)
// ---------------------------------------------------------------------------
__global__ __launch_bounds__(256) void prep_w(
    const float* __restrict__ w_ih_f, const float* __restrict__ w_hh_f,
    const float* __restrict__ b_f, const float* __restrict__ w_ih_b,
    const float* __restrict__ w_hh_b, const float* __restrict__ b_b,
    unsigned char* __restrict__ Wt, float* __restrict__ bp)
{
    int idx = blockIdx.x * 256 + threadIdx.x;   // exactly 786432 total
    int e  = idx & 7;
    int cu = (idx >> 3) & 127;      // f*16+u
    int hi = (idx >> 10) & 3;
    int rest = idx >> 12;           // dw*12 + kk
    int kk = rest % 12;
    int dw = rest / 12;             // dir*8 + wv
    int wv = dw & 7, dir = dw >> 3;
    int f = cu >> 4, u = cu & 15;
    int q = f >> 2, g = f & 3;
    int j = wv * 32 + q * 16 + u;
    int row = g * H_SZ + j;
    int k = kk * 32 + hi * 8 + e;
    const float* w_ih = dir ? w_ih_b : w_ih_f;
    const float* w_hh = dir ? w_hh_b : w_hh_f;
    float v = (k < H_SZ) ? w_hh[row * H_SZ + k] : w_ih[row * D_SZ + (k - H_SZ)];
    Wt[idx] = f2fp8(v);
    if (kk == 0 && hi == 0 && e == 0)
        bp[dw * 128 + cu] = (dir ? b_b : b_f)[row];
}

__global__ __launch_bounds__(256) void prep_aw(
    const float* __restrict__ aw1, short* __restrict__ aw1b)
{
    int idx = blockIdx.x * 256 + threadIdx.x;
    if (idx < H_SZ * E_SZ) aw1b[idx] = (short)f2bf(aw1[idx]);
}

// x fp32 -> fp8 e4m3, same [B][T][D] layout
__global__ __launch_bounds__(256) void xprep(
    const float* __restrict__ x, unsigned char* __restrict__ xb)
{
    size_t i = ((size_t)blockIdx.x * 256 + threadIdx.x) * 4;
    float4 v = *reinterpret_cast<const float4*>(x + i);
    int p0 = __builtin_amdgcn_cvt_pk_fp8_f32(v.x, v.y, 0, false);
    int p1 = __builtin_amdgcn_cvt_pk_fp8_f32(v.z, v.w, 0, false);
    unsigned w = (unsigned)(p0 & 0xffff) | ((unsigned)p1 << 16);
    *reinterpret_cast<unsigned*>(xb + i) = w;
}

// ---------------------------------------------------------------------------
// Persistent BiLSTM, fp8 weights resident: 80 frags/lane in AGPRs (asm-pinned)
// + 16 frags in LDS. 64 blocks = 32 batch-tiles(16 rows) x 2 dirs, 512 thr.
// Wave wv owns 128 gate-cols = cells [wv*32, wv*32+32) x 4 gates.
// ---------------------------------------------------------------------------
__global__ __launch_bounds__(512)
__attribute__((amdgpu_waves_per_eu(2, 2)))
void recur_kernel(
    const unsigned char* __restrict__ xb, const unsigned char* __restrict__ Wt,
    const float* __restrict__ bp, unsigned short* __restrict__ hb)
{
    const int dir = blockIdx.x & 1;
    const int b0 = (blockIdx.x >> 1) * 16;
    const int wv = threadIdx.x >> 6;
    const int l  = threadIdx.x & 63;
    const int u = l & 15, hi = l >> 4;

    __shared__ unsigned char hs[2][16][264];   // fp8 h, padded rows
    __shared__ unsigned char xs[2][16][136];   // fp8 x_t, padded rows
    __shared__ long wlds[128][64];             // weight slices kk=10,11 (64KB)

    // zero hs[0] (h at t=-1): 4224B = 1056 dwords
    for (int i = threadIdx.x; i < 1056; i += 512)
        reinterpret_cast<unsigned*>(&hs[0][0][0])[i] = 0u;

    // copy weight slices kk=10,11 (this block's dir) into LDS
    for (int i = threadIdx.x; i < 128 * 64; i += 512) {
        int slabf = i >> 6;             // wv*16 + kkr*8 + f
        int ll = i & 63;
        int wvv = slabf >> 4;
        int kkr = (slabf >> 3) & 1;
        int ff = slabf & 7;
        int hi2 = ll >> 4, uu = ll & 15;
        int dww = dir * 8 + wvv;
        wlds[slabf][ll] = *reinterpret_cast<const long*>(
            Wt + (((size_t)(dww * 12 + 10 + kkr) * 4 + hi2) * 128 + (ff * 16 + uu)) * 8);
    }

    // resident fp8 weights kk=0..9: 80 frags/lane = 160 AGPRs
    // volatile: exactly-once load; "a"-constrained use pins them in AGPRs
    const int dw = dir * 8 + wv;
    const unsigned char* wb = Wt + (size_t)dw * 49152 + hi * 1024 + u * 8;
    long wrega[10][8];
    #pragma unroll
    for (int kk = 0; kk < 10; ++kk)
        #pragma unroll
        for (int f = 0; f < 8; ++f)
            wrega[kk][f] = *reinterpret_cast<const volatile long*>(wb + kk * 4096 + f * 128);

    float bias[8];
    #pragma unroll
    for (int f = 0; f < 8; ++f)
        bias[f] = bp[dw * 128 + f * 16 + u];

    // x staging: thread covers (row = tid>>5, 4 bytes at (tid&31)*4)
    const int xrow = threadIdx.x >> 5;
    const int xoff = (threadIdx.x & 31) * 4;
    const unsigned char* xbase = xb + (size_t)(b0 + xrow) * T_SZ * D_SZ + xoff;
    const int tstep = dir ? -1 : 1;
    const int t0 = dir ? (T_SZ - 1) : 0;
    *reinterpret_cast<unsigned*>(&xs[0][xrow][xoff]) =
        *reinterpret_cast<const unsigned*>(xbase + (size_t)t0 * D_SZ);
    unsigned xreg = *reinterpret_cast<const unsigned*>(
        xbase + (size_t)(t0 + tstep) * D_SZ);

    float c[2][4] = {};
    int cur = 0;
    __syncthreads();   // hs[0] zero + xs[0] + wlds visible

    for (int s = 0; s < T_SZ; ++s) {
        const int t = dir ? (T_SZ - 1 - s) : s;

        // stage next x into the other buffer; prefetch s+2
        if (s + 1 < T_SZ) {
            *reinterpret_cast<unsigned*>(&xs[(s + 1) & 1][xrow][xoff]) = xreg;
            if (s + 2 < T_SZ)
                xreg = *reinterpret_cast<const unsigned*>(
                    xbase + (size_t)(t + 2 * tstep) * D_SZ);
        }

        f32x4 acc[8];
        #pragma unroll
        for (int f = 0; f < 8; ++f)
            acc[f] = (f32x4){bias[f], bias[f], bias[f], bias[f]};

        // kk = 0..7: h-recurrent slices (AGPR weights)
        #pragma unroll
        for (int kk = 0; kk < 8; ++kk) {
            long a = *reinterpret_cast<const long*>(&hs[cur][u][kk * 32 + hi * 8]);
            #pragma unroll
            for (int f = 0; f < 8; ++f)
                mfma_fp8_a(acc[f], a, wrega[kk][f]);
        }
        // kk = 8..9: x slices 0,1 (AGPR weights)
        #pragma unroll
        for (int kk = 8; kk < 10; ++kk) {
            long a = *reinterpret_cast<const long*>(&xs[s & 1][u][(kk - 8) * 32 + hi * 8]);
            #pragma unroll
            for (int f = 0; f < 8; ++f)
                mfma_fp8_a(acc[f], a, wrega[kk][f]);
        }
        // kk = 10..11: x slices 2,3 (LDS weights, builtin MFMA)
        #pragma unroll
        for (int kkr = 0; kkr < 2; ++kkr) {
            long a = *reinterpret_cast<const long*>(&xs[s & 1][u][(2 + kkr) * 32 + hi * 8]);
            #pragma unroll
            for (int f = 0; f < 8; ++f)
                acc[f] = __builtin_amdgcn_mfma_f32_16x16x32_fp8_fp8(
                    a, wlds[wv * 16 + kkr * 8 + f][l], acc[f], 0, 0, 0);
        }
        // hazard insurance: MFMA results -> VALU epilogue
        asm volatile("s_nop 7\n\ts_nop 3" ::);

        // epilogue: lane -> rows hi*4+r, cells j = wv*32 + q*16 + u
        #pragma unroll
        for (int q = 0; q < 2; ++q) {
            const int j = wv * 32 + q * 16 + u;
            #pragma unroll
            for (int r = 0; r < 4; ++r) {
                float iv = fsigm(acc[q * 4 + 0][r]);
                float fv = fsigm(acc[q * 4 + 1][r]);
                float gv = ftanh(acc[q * 4 + 2][r]);
                float ov = fsigm(acc[q * 4 + 3][r]);
                float cn = fv * c[q][r] + iv * gv;
                c[q][r] = cn;
                float h = ov * ftanh(cn);
                int row = hi * 4 + r;
                hs[cur ^ 1][row][j] = f2fp8(h);
                hb[((size_t)t * B_SZ + b0 + row) * E_SZ + dir * H_SZ + j] = f2bf(h);
            }
        }
        __syncthreads();   // step-s writes visible; step-s reads complete
        cur ^= 1;
    }
}

// ---------------------------------------------------------------------------
// Attention MLP scores, bf16 MFMA
// ---------------------------------------------------------------------------
__global__ __launch_bounds__(256) void attn_mfma(
    const unsigned short* __restrict__ hb, const short* __restrict__ aw1b,
    const float* __restrict__ ab1, const float* __restrict__ aw2,
    float* __restrict__ scores)
{
    const int mt = blockIdx.x >> 1, nt = blockIdx.x & 1;
    const int r0 = mt * 128, n0 = nt * 128;
    const int tid = threadIdx.x;
    const int wv = tid >> 6, l = tid & 63, u = l & 15, hi = l >> 4;
    const int mw = wv >> 1, nw = wv & 1;

    __shared__ unsigned short As[128][40];
    __shared__ unsigned short Bs[128][40];

    f32x4 acc[4][4];
    #pragma unroll
    for (int m = 0; m < 4; ++m)
        #pragma unroll
        for (int n = 0; n < 4; ++n)
            acc[m][n] = (f32x4){0.f, 0.f, 0.f, 0.f};

    const int srow = tid >> 1;
    const int sc0 = (tid & 1) * 16;

    for (int k0 = 0; k0 < E_SZ; k0 += 32) {
        bf16x8 va0 = *reinterpret_cast<const bf16x8*>(hb + (size_t)(r0 + srow) * E_SZ + k0 + sc0);
        bf16x8 va1 = *reinterpret_cast<const bf16x8*>(hb + (size_t)(r0 + srow) * E_SZ + k0 + sc0 + 8);
        bf16x8 vb0 = *reinterpret_cast<const bf16x8*>(aw1b + (size_t)(n0 + srow) * E_SZ + k0 + sc0);
        bf16x8 vb1 = *reinterpret_cast<const bf16x8*>(aw1b + (size_t)(n0 + srow) * E_SZ + k0 + sc0 + 8);
        __syncthreads();
        *reinterpret_cast<bf16x8*>(&As[srow][sc0])     = va0;
        *reinterpret_cast<bf16x8*>(&As[srow][sc0 + 8]) = va1;
        *reinterpret_cast<bf16x8*>(&Bs[srow][sc0])     = vb0;
        *reinterpret_cast<bf16x8*>(&Bs[srow][sc0 + 8]) = vb1;
        __syncthreads();

        bf16x8 af[4], bf[4];
        #pragma unroll
        for (int m = 0; m < 4; ++m)
            af[m] = *reinterpret_cast<const bf16x8*>(&As[mw * 64 + m * 16 + u][hi * 8]);
        #pragma unroll
        for (int n = 0; n < 4; ++n)
            bf[n] = *reinterpret_cast<const bf16x8*>(&Bs[nw * 64 + n * 16 + u][hi * 8]);
        #pragma unroll
        for (int m = 0; m < 4; ++m)
            #pragma unroll
            for (int n = 0; n < 4; ++n)
                acc[m][n] = __builtin_amdgcn_mfma_f32_16x16x32_bf16(af[m], bf[n], acc[m][n], 0, 0, 0);
    }

    float t1[4], t2[4];
    #pragma unroll
    for (int n = 0; n < 4; ++n) {
        int h = n0 + nw * 64 + n * 16 + u;
        t1[n] = ab1[h]; t2[n] = aw2[h];
    }
    #pragma unroll
    for (int m = 0; m < 4; ++m) {
        #pragma unroll
        for (int r = 0; r < 4; ++r) {
            float s = 0.f;
            #pragma unroll
            for (int n = 0; n < 4; ++n)
                s += tanhf(acc[m][n][r] + t1[n]) * t2[n];
            #pragma unroll
            for (int o = 1; o < 16; o <<= 1) s += __shfl_xor(s, o);
            if (u == 0)
                atomicAdd(&scores[r0 + mw * 64 + m * 16 + hi * 4 + r], s);
        }
    }
}

// ---------------------------------------------------------------------------
// Per-batch softmax over T + pooling -> features[b][512]
// ---------------------------------------------------------------------------
__global__ __launch_bounds__(256) void attn_pool(
    const float* __restrict__ scores, const unsigned short* __restrict__ hb,
    float* __restrict__ features)
{
    int b = blockIdx.x;
    int tid = threadIdx.x;
    __shared__ float w[T_SZ];
    __shared__ float smax[4], ssum[4];

    float sc = (tid < T_SZ) ? scores[(size_t)tid * B_SZ + b] : -INFINITY;
    float m = sc;
    for (int o = 32; o; o >>= 1) m = fmaxf(m, __shfl_xor(m, o));
    if ((tid & 63) == 0) smax[tid >> 6] = m;
    __syncthreads();
    float M = fmaxf(fmaxf(smax[0], smax[1]), fmaxf(smax[2], smax[3]));
    float e = (tid < T_SZ) ? expf(sc - M) : 0.f;
    float se = e;
    for (int o = 32; o; o >>= 1) se += __shfl_xor(se, o);
    if ((tid & 63) == 0) ssum[tid >> 6] = se;
    __syncthreads();
    float S = ssum[0] + ssum[1] + ssum[2] + ssum[3];
    if (tid < T_SZ) w[tid] = e / S;
    __syncthreads();

    for (int e0 = tid; e0 < E_SZ; e0 += 256) {
        float acc = 0.f;
        for (int t = 0; t < T_SZ; ++t)
            acc += w[t] * bf2f(hb[((size_t)t * B_SZ + b) * E_SZ + e0]);
        features[(size_t)b * E_SZ + e0] = acc;
    }
}

// ---------------------------------------------------------------------------
// FC: 64 blocks x 8 batch rows
// ---------------------------------------------------------------------------
__global__ __launch_bounds__(256) void fc_kernel(
    const float* __restrict__ features, const float* __restrict__ fc_w,
    const float* __restrict__ fc_b, float* __restrict__ logits)
{
    int bb = blockIdx.x * 8;
    int tid = threadIdx.x;
    __shared__ float f[8][E_SZ];
    for (int i = tid; i < 8 * E_SZ; i += 256)
        f[i >> 9][i & 511] = features[(size_t)(bb + (i >> 9)) * E_SZ + (i & 511)];
    __syncthreads();
    for (int o = tid; o < K_SZ * L_SZ; o += 256) {
        const float* wr = fc_w + (size_t)o * E_SZ;
        float acc[8];
        float bv = fc_b[o];
        #pragma unroll
        for (int b = 0; b < 8; ++b) acc[b] = bv;
        for (int e0 = 0; e0 < E_SZ; ++e0) {
            float wv = wr[e0];
            #pragma unroll
            for (int b = 0; b < 8; ++b) acc[b] += f[b][e0] * wv;
        }
        #pragma unroll
        for (int b = 0; b < 8; ++b)
            logits[(size_t)(bb + b) * (K_SZ * L_SZ) + o] = acc[b];
    }
}

// ---------------------------------------------------------------------------
// CRF loss per batch element
// ---------------------------------------------------------------------------
__global__ __launch_bounds__(64) void crf_kernel(
    const float* __restrict__ logits, const int* __restrict__ labels,
    const float* __restrict__ start_t, const float* __restrict__ trans,
    const float* __restrict__ end_t, float* __restrict__ per_loss)
{
    int b = blockIdx.x;
    int tid = threadIdx.x;
    __shared__ float tr[K_SZ * K_SZ];
    __shared__ float em[K_SZ * L_SZ];
    __shared__ float alpha[K_SZ];

    for (int i = tid; i < K_SZ * K_SZ; i += 64) tr[i] = trans[i];
    for (int i = tid; i < K_SZ * L_SZ; i += 64)
        em[i] = logits[(size_t)b * (K_SZ * L_SZ) + i];
    __syncthreads();
    if (tid < K_SZ) alpha[tid] = start_t[tid] + em[tid];
    __syncthreads();

    for (int t = 1; t < L_SZ; ++t) {
        float na = 0.f;
        if (tid < K_SZ) {
            float m = -INFINITY;
            for (int k = 0; k < K_SZ; ++k)
                m = fmaxf(m, alpha[k] + tr[k * K_SZ + tid]);
            float s = 0.f;
            for (int k = 0; k < K_SZ; ++k)
                s += expf(alpha[k] + tr[k * K_SZ + tid] - m);
            na = m + logf(s) + em[t * K_SZ + tid];
        }
        __syncthreads();
        if (tid < K_SZ) alpha[tid] = na;
        __syncthreads();
    }

    float v = (tid < K_SZ) ? alpha[tid] + end_t[tid] : -INFINITY;
    float m = v;
    for (int o = 32; o; o >>= 1) m = fmaxf(m, __shfl_xor(m, o));
    float e = (tid < K_SZ) ? expf(v - m) : 0.f;
    for (int o = 32; o; o >>= 1) e += __shfl_xor(e, o);
    float logZ = m + logf(e);

    if (tid == 0) {
        const int* lab = labels + (size_t)b * L_SZ;
        float score = start_t[lab[0]] + end_t[lab[L_SZ - 1]];
        for (int t = 0; t < L_SZ; ++t) score += em[t * K_SZ + lab[t]];
        for (int t = 0; t < L_SZ - 1; ++t) score += tr[lab[t] * K_SZ + lab[t + 1]];
        per_loss[b] = logZ - score;
    }
}

__global__ __launch_bounds__(256) void reduce_kernel(
    const float* __restrict__ per_loss, float* __restrict__ out)
{
    int tid = threadIdx.x;
    float s = per_loss[tid] + per_loss[tid + 256];
    for (int o = 32; o; o >>= 1) s += __shfl_xor(s, o);
    __shared__ float part[4];
    if ((tid & 63) == 0) part[tid >> 6] = s;
    __syncthreads();
    if (tid == 0) out[0] = (part[0] + part[1] + part[2] + part[3]) / (float)B_SZ;
}

// ---------------------------------------------------------------------------
extern "C" void kernel_launch(void* const* d_in, const int* in_sizes, int n_in,
                              void* d_out, int out_size, void* d_ws, size_t ws_size,
                              hipStream_t stream)
{
    const float* x      = (const float*)d_in[0];
    const int*   labels = (const int*)d_in[1];
    const float* w_ih_f = (const float*)d_in[2];
    const float* w_hh_f = (const float*)d_in[3];
    const float* b_f    = (const float*)d_in[4];
    const float* w_ih_b = (const float*)d_in[5];
    const float* w_hh_b = (const float*)d_in[6];
    const float* b_b    = (const float*)d_in[7];
    const float* aw1    = (const float*)d_in[8];
    const float* ab1    = (const float*)d_in[9];
    const float* aw2    = (const float*)d_in[10];
    // d_in[11] = ab2 : softmax-invariant, unused
    const float* fc_w   = (const float*)d_in[12];
    const float* fc_b   = (const float*)d_in[13];
    const float* start_t = (const float*)d_in[14];
    const float* trans   = (const float*)d_in[15];
    const float* end_t   = (const float*)d_in[16];
    float* out = (float*)d_out;

    char* ws = (char*)d_ws;
    size_t off = 0;
    unsigned char* Wt = (unsigned char*)(ws + off); off += (size_t)786432;            // fp8 weights
    float* bp        = (float*)(ws + off); off += (size_t)2048 * 4;                   // 8KB
    short* aw1b      = (short*)(ws + off); off += (size_t)H_SZ * E_SZ * 2;            // 256KB
    unsigned char* xb = (unsigned char*)(ws + off); off += (size_t)B_SZ * T_SZ * D_SZ; // 8.4MB fp8
    unsigned short* hb = (unsigned short*)(ws + off); off += (size_t)T_SZ * B_SZ * E_SZ * 2; // 67MB
    float* scores    = (float*)(ws + off); off += (size_t)T_SZ * B_SZ * 4;
    float* features  = (float*)(ws + off); off += (size_t)B_SZ * E_SZ * 4;
    float* logits    = (float*)(ws + off); off += (size_t)B_SZ * K_SZ * L_SZ * 4;
    float* per_loss  = (float*)(ws + off); off += (size_t)B_SZ * 4;

    // 1. weight/bias/x prep
    prep_w<<<3072, 256, 0, stream>>>(
        w_ih_f, w_hh_f, b_f, w_ih_b, w_hh_b, b_b, Wt, bp);
    prep_aw<<<(H_SZ * E_SZ + 255) / 256, 256, 0, stream>>>(aw1, aw1b);
    xprep<<<(B_SZ * T_SZ * D_SZ / 4 + 255) / 256, 256, 0, stream>>>(x, xb);

    // 2. zero score accumulator
    hipMemsetAsync(scores, 0, (size_t)T_SZ * B_SZ * 4, stream);

    // 3. BiLSTM — persistent, weights AGPR-pinned (inline-asm MFMA) + LDS
    recur_kernel<<<64, 512, 0, stream>>>(xb, Wt, bp, hb);

    // 4. attention MLP scores (bf16 MFMA)
    attn_mfma<<<1024, 256, 0, stream>>>(hb, aw1b, ab1, aw2, scores);

    // 5. softmax + pooling
    attn_pool<<<B_SZ, 256, 0, stream>>>(scores, hb, features);

    // 6. FC to emissions
    fc_kernel<<<64, 256, 0, stream>>>(features, fc_w, fc_b, logits);

    // 7. CRF loss
    crf_kernel<<<B_SZ, 64, 0, stream>>>(logits, labels, start_t, trans, end_t, per_loss);

    // 8. mean
    reduce_kernel<<<1, 256, 0, stream>>>(per_loss, out);
}

// Round 9
// 824.552 us; speedup vs baseline: 1.2278x; 1.2278x over previous
//
#include <hip/hip_runtime.h>
#include <math.h>

// Problem constants
#define B_SZ 512
#define T_SZ 128
#define D_SZ 128
#define H_SZ 256
#define K_SZ 49
#define L_SZ 7
#define E_SZ 512   // 2H

typedef float f32x4 __attribute__((ext_vector_type(4)));
typedef short bf16x8 __attribute__((ext_vector_type(8)));

__device__ __forceinline__ unsigned short f2bf(float f) {
    union { float f; unsigned u; } v; v.f = f;
    unsigned r = v.u + 0x7FFFu + ((v.u >> 16) & 1u);
    return (unsigned short)(r >> 16);
}
__device__ __forceinline__ float bf2f(unsigned short h) {
    union { unsigned u; float f; } v; v.u = ((unsigned)h) << 16;
    return v.f;
}
__device__ __forceinline__ float fsigm(float x) {
    return __fdividef(1.0f, 1.0f + __expf(-x));
}
__device__ __forceinline__ float ftanh(float x) {
    x = fminf(fmaxf(x, -20.0f), 20.0f);
    float e = __expf(2.0f * x);
    return __fdividef(e - 1.0f, e + 1.0f);
}
__device__ __forceinline__ unsigned char f2fp8(float v) {
    int p = __builtin_amdgcn_cvt_pk_fp8_f32(v, 0.f, 0, false);
    return (unsigned char)(p & 0xff);
}
// fp8 e4m3 -> f32: ((b&0x7f)<<20 | sign<<31) bitcast * 2^120 handles both
// normal and subnormal cases exactly.
__device__ __forceinline__ float dec_fp8(unsigned b) {
    union { unsigned u; float f; } v;
    v.u = ((b & 0x7Fu) << 20) | ((b & 0x80u) << 24);
    return v.f * 0x1.0p120f;
}

// ---------------------------------------------------------------------------
// Recurrent (w_hh) weight prep, fp8 frag order for 16 waves/dir:
// idx bits: e(3) u(4) g(2) hi(2) kk(3) wv(4) dir(1)  -> 2^19 = 524288 bytes
// frag(dw,kk,hi,g) holds cols (cell j=wv*16+u, gate g), k = kk*32+hi*8+e
// ---------------------------------------------------------------------------
__global__ __launch_bounds__(256) void prep_whh(
    const float* __restrict__ w_hh_f, const float* __restrict__ w_hh_b,
    unsigned char* __restrict__ Wt)
{
    int idx = blockIdx.x * 256 + threadIdx.x;   // 524288 total
    int e  = idx & 7;
    int u  = (idx >> 3) & 15;
    int g  = (idx >> 7) & 3;
    int hi = (idx >> 9) & 3;
    int kk = (idx >> 11) & 7;
    int wv = (idx >> 14) & 15;
    int dir = idx >> 18;
    int j = wv * 16 + u;
    int row = g * H_SZ + j;
    int k = kk * 32 + hi * 8 + e;
    const float* w_hh = dir ? w_hh_b : w_hh_f;
    Wt[idx] = f2fp8(w_hh[row * H_SZ + k]);
}

// ---------------------------------------------------------------------------
// Input (w_ih) weight prep into fp8 [2048 cols][128 k] + combined bias.
// col c: dir=c>>10, cc=c&1023, wv=cc>>6, u=(cc>>2)&15, g=cc&3 ;
// cell j=wv*16+u, orig row g*256+j.
// ---------------------------------------------------------------------------
__global__ __launch_bounds__(256) void prep_wih(
    const float* __restrict__ w_ih_f, const float* __restrict__ b_f,
    const float* __restrict__ w_ih_b, const float* __restrict__ b_b,
    unsigned char* __restrict__ Wp, float* __restrict__ biasp)
{
    int idx = blockIdx.x * 256 + threadIdx.x;   // 262144 total
    int k = idx & 127;
    int c = idx >> 7;
    int dir = c >> 10;
    int cc = c & 1023;
    int wv = cc >> 6, u = (cc >> 2) & 15, g = cc & 3;
    int row = g * H_SZ + wv * 16 + u;
    const float* w_ih = dir ? w_ih_b : w_ih_f;
    Wp[(size_t)c * D_SZ + k] = f2fp8(w_ih[row * D_SZ + k]);
    if (k == 0) biasp[c] = (dir ? b_b : b_f)[row];
}

__global__ __launch_bounds__(256) void prep_aw(
    const float* __restrict__ aw1, short* __restrict__ aw1b)
{
    int idx = blockIdx.x * 256 + threadIdx.x;
    if (idx < H_SZ * E_SZ) aw1b[idx] = (short)f2bf(aw1[idx]);
}

// x fp32 -> fp8 e4m3, same [B][T][D] layout
__global__ __launch_bounds__(256) void xprep(
    const float* __restrict__ x, unsigned char* __restrict__ xb)
{
    size_t i = ((size_t)blockIdx.x * 256 + threadIdx.x) * 4;
    float4 v = *reinterpret_cast<const float4*>(x + i);
    int p0 = __builtin_amdgcn_cvt_pk_fp8_f32(v.x, v.y, 0, false);
    int p1 = __builtin_amdgcn_cvt_pk_fp8_f32(v.z, v.w, 0, false);
    unsigned w = (unsigned)(p0 & 0xffff) | ((unsigned)p1 << 16);
    *reinterpret_cast<unsigned*>(xb + i) = w;
}

// ---------------------------------------------------------------------------
// x-projection GEMM (fp8 MFMA): xp[m][c] = fp8( x[m] . Wp[c] + biasp[c] )
// m = t*512 + b (rows), c = permuted gate col (2048). 8192 blocks:
// 512 m-tiles(128) x 16 n-tiles(128); 4 waves of 64x64; K=128 staged once.
// LDS rows padded to 144 B (multiple of 16: ds_write_b128 must be 16B-aligned;
// 136 was the round-8 MEM_VIOL crasher).
// ---------------------------------------------------------------------------
__global__ __launch_bounds__(256) void xproj_gemm(
    const unsigned char* __restrict__ xb, const unsigned char* __restrict__ Wp,
    const float* __restrict__ biasp, unsigned char* __restrict__ xp)
{
    const int mt = blockIdx.x >> 4;
    const int nt = blockIdx.x & 15;
    const int r0 = mt * 128, n0 = nt * 128;
    const int t = r0 >> 9;            // constant within block
    const int b0 = r0 & 511;
    const int tid = threadIdx.x;
    const int wv = tid >> 6, l = tid & 63, u = l & 15, hi = l >> 4;
    const int mw = wv >> 1, nw = wv & 1;

    __shared__ unsigned char As[128][144];
    __shared__ unsigned char Bs[128][144];

    {
        int row = tid & 127;
        int q0 = (tid >> 7) * 16;     // 0 or 16
        const unsigned char* xr = xb + ((size_t)(b0 + row) * T_SZ + t) * D_SZ;
        const unsigned char* wr = Wp + (size_t)(n0 + row) * D_SZ;
        #pragma unroll
        for (int q = 0; q < 128; q += 32) {
            *reinterpret_cast<uint4*>(&As[row][q + q0]) =
                *reinterpret_cast<const uint4*>(xr + q + q0);
            *reinterpret_cast<uint4*>(&Bs[row][q + q0]) =
                *reinterpret_cast<const uint4*>(wr + q + q0);
        }
    }
    __syncthreads();

    f32x4 acc[4][4];
    #pragma unroll
    for (int m = 0; m < 4; ++m)
        #pragma unroll
        for (int n = 0; n < 4; ++n)
            acc[m][n] = (f32x4){0.f, 0.f, 0.f, 0.f};

    #pragma unroll
    for (int kk = 0; kk < 4; ++kk) {
        long af[4], bf[4];
        #pragma unroll
        for (int m = 0; m < 4; ++m)
            af[m] = *reinterpret_cast<const long*>(&As[mw * 64 + m * 16 + u][kk * 32 + hi * 8]);
        #pragma unroll
        for (int n = 0; n < 4; ++n)
            bf[n] = *reinterpret_cast<const long*>(&Bs[nw * 64 + n * 16 + u][kk * 32 + hi * 8]);
        #pragma unroll
        for (int m = 0; m < 4; ++m)
            #pragma unroll
            for (int n = 0; n < 4; ++n)
                acc[m][n] = __builtin_amdgcn_mfma_f32_16x16x32_fp8_fp8(af[m], bf[n], acc[m][n], 0, 0, 0);
    }

    float bias[4];
    #pragma unroll
    for (int n = 0; n < 4; ++n) bias[n] = biasp[n0 + nw * 64 + n * 16 + u];

    #pragma unroll
    for (int m = 0; m < 4; ++m) {
        #pragma unroll
        for (int r = 0; r < 4; ++r) {
            size_t mrow = (size_t)r0 + mw * 64 + m * 16 + hi * 4 + r;
            unsigned char* orow = xp + mrow * 2048 + n0 + nw * 64;
            #pragma unroll
            for (int n = 0; n < 4; ++n)
                orow[n * 16 + u] = f2fp8(acc[m][n][r] + bias[n]);
        }
    }
}

// ---------------------------------------------------------------------------
// Persistent BiLSTM, recurrent-only (K=256), x-projection pre-folded.
// 64 blocks = 32 batch-tiles(16 rows) x 2 dirs, 1024 threads = 16 waves.
// Wave wv owns 64 gate-cols = cells [wv*16, wv*16+16) x 4 gates.
// Weights: 32 fp8 frags/lane = 64 VGPR. acc init = prefetched xp (fp8).
// ---------------------------------------------------------------------------
__global__ __launch_bounds__(1024) void recur_kernel(
    const unsigned char* __restrict__ xp, const unsigned char* __restrict__ Wt,
    unsigned short* __restrict__ hb)
{
    const int dir = blockIdx.x & 1;
    const int b0 = (blockIdx.x >> 1) * 16;
    const int wv = threadIdx.x >> 6;
    const int l  = threadIdx.x & 63;
    const int u = l & 15, hi = l >> 4;

    __shared__ unsigned char hs[2][16][264];   // fp8 h, padded rows

    for (int i = threadIdx.x; i < 1056; i += 1024)
        reinterpret_cast<unsigned*>(&hs[0][0][0])[i] = 0u;

    // resident fp8 w_hh: 32 frags/lane = 64 VGPR (volatile: exactly-once)
    const int dw = dir * 16 + wv;
    const unsigned char* wb = Wt + (size_t)dw * 16384 + hi * 512 + u * 8;
    long wreg[8][4];
    #pragma unroll
    for (int kk = 0; kk < 8; ++kk)
        #pragma unroll
        for (int g = 0; g < 4; ++g)
            wreg[kk][g] = *reinterpret_cast<const volatile long*>(wb + kk * 2048 + g * 128);

    const int tstep = dir ? -1 : 1;
    const int t0 = dir ? (T_SZ - 1) : 0;
    const int j = wv * 16 + u;
    const size_t xcol = (size_t)dir * 1024 + wv * 64 + u * 4;

    // prefetch xp (4 gates x 4 rows, fp8) for step 0
    unsigned xpre[4];
    #pragma unroll
    for (int r = 0; r < 4; ++r)
        xpre[r] = *reinterpret_cast<const unsigned*>(
            xp + ((size_t)(t0 * B_SZ + b0 + hi * 4 + r)) * 2048 + xcol);

    float c[4] = {0.f, 0.f, 0.f, 0.f};
    int cur = 0;
    __syncthreads();   // hs[0] zero visible

    for (int s = 0; s < T_SZ; ++s) {
        const int t = dir ? (T_SZ - 1 - s) : s;

        // acc init from x-projection (consumes xpre)
        f32x4 acc[4];
        #pragma unroll
        for (int g = 0; g < 4; ++g)
            #pragma unroll
            for (int r = 0; r < 4; ++r)
                acc[g][r] = dec_fp8((xpre[r] >> (g * 8)) & 0xffu);

        // prefetch next step's xp
        if (s + 1 < T_SZ) {
            int tn = t + tstep;
            #pragma unroll
            for (int r = 0; r < 4; ++r)
                xpre[r] = *reinterpret_cast<const unsigned*>(
                    xp + ((size_t)(tn * B_SZ + b0 + hi * 4 + r)) * 2048 + xcol);
        }

        // h-recurrence: K=256, 8 slices x 4 gate-blocks
        #pragma unroll
        for (int kk = 0; kk < 8; ++kk) {
            long a = *reinterpret_cast<const long*>(&hs[cur][u][kk * 32 + hi * 8]);
            #pragma unroll
            for (int g = 0; g < 4; ++g)
                acc[g] = __builtin_amdgcn_mfma_f32_16x16x32_fp8_fp8(a, wreg[kk][g], acc[g], 0, 0, 0);
        }

        // epilogue: lane -> rows hi*4+r, single cell j
        #pragma unroll
        for (int r = 0; r < 4; ++r) {
            float iv = fsigm(acc[0][r]);
            float fv = fsigm(acc[1][r]);
            float gv = ftanh(acc[2][r]);
            float ov = fsigm(acc[3][r]);
            float cn = fv * c[r] + iv * gv;
            c[r] = cn;
            float h = ov * ftanh(cn);
            int row = hi * 4 + r;
            hs[cur ^ 1][row][j] = f2fp8(h);
            hb[((size_t)t * B_SZ + b0 + row) * E_SZ + dir * H_SZ + j] = f2bf(h);
        }
        __syncthreads();   // step-s hs writes visible; step-s reads complete
        cur ^= 1;
    }
}

// ---------------------------------------------------------------------------
// Attention MLP scores, bf16 MFMA
// ---------------------------------------------------------------------------
__global__ __launch_bounds__(256) void attn_mfma(
    const unsigned short* __restrict__ hb, const short* __restrict__ aw1b,
    const float* __restrict__ ab1, const float* __restrict__ aw2,
    float* __restrict__ scores)
{
    const int mt = blockIdx.x >> 1, nt = blockIdx.x & 1;
    const int r0 = mt * 128, n0 = nt * 128;
    const int tid = threadIdx.x;
    const int wv = tid >> 6, l = tid & 63, u = l & 15, hi = l >> 4;
    const int mw = wv >> 1, nw = wv & 1;

    __shared__ unsigned short As[128][40];
    __shared__ unsigned short Bs[128][40];

    f32x4 acc[4][4];
    #pragma unroll
    for (int m = 0; m < 4; ++m)
        #pragma unroll
        for (int n = 0; n < 4; ++n)
            acc[m][n] = (f32x4){0.f, 0.f, 0.f, 0.f};

    const int srow = tid >> 1;
    const int sc0 = (tid & 1) * 16;

    for (int k0 = 0; k0 < E_SZ; k0 += 32) {
        bf16x8 va0 = *reinterpret_cast<const bf16x8*>(hb + (size_t)(r0 + srow) * E_SZ + k0 + sc0);
        bf16x8 va1 = *reinterpret_cast<const bf16x8*>(hb + (size_t)(r0 + srow) * E_SZ + k0 + sc0 + 8);
        bf16x8 vb0 = *reinterpret_cast<const bf16x8*>(aw1b + (size_t)(n0 + srow) * E_SZ + k0 + sc0);
        bf16x8 vb1 = *reinterpret_cast<const bf16x8*>(aw1b + (size_t)(n0 + srow) * E_SZ + k0 + sc0 + 8);
        __syncthreads();
        *reinterpret_cast<bf16x8*>(&As[srow][sc0])     = va0;
        *reinterpret_cast<bf16x8*>(&As[srow][sc0 + 8]) = va1;
        *reinterpret_cast<bf16x8*>(&Bs[srow][sc0])     = vb0;
        *reinterpret_cast<bf16x8*>(&Bs[srow][sc0 + 8]) = vb1;
        __syncthreads();

        bf16x8 af[4], bf[4];
        #pragma unroll
        for (int m = 0; m < 4; ++m)
            af[m] = *reinterpret_cast<const bf16x8*>(&As[mw * 64 + m * 16 + u][hi * 8]);
        #pragma unroll
        for (int n = 0; n < 4; ++n)
            bf[n] = *reinterpret_cast<const bf16x8*>(&Bs[nw * 64 + n * 16 + u][hi * 8]);
        #pragma unroll
        for (int m = 0; m < 4; ++m)
            #pragma unroll
            for (int n = 0; n < 4; ++n)
                acc[m][n] = __builtin_amdgcn_mfma_f32_16x16x32_bf16(af[m], bf[n], acc[m][n], 0, 0, 0);
    }

    float t1[4], t2[4];
    #pragma unroll
    for (int n = 0; n < 4; ++n) {
        int h = n0 + nw * 64 + n * 16 + u;
        t1[n] = ab1[h]; t2[n] = aw2[h];
    }
    #pragma unroll
    for (int m = 0; m < 4; ++m) {
        #pragma unroll
        for (int r = 0; r < 4; ++r) {
            float s = 0.f;
            #pragma unroll
            for (int n = 0; n < 4; ++n)
                s += tanhf(acc[m][n][r] + t1[n]) * t2[n];
            #pragma unroll
            for (int o = 1; o < 16; o <<= 1) s += __shfl_xor(s, o);
            if (u == 0)
                atomicAdd(&scores[r0 + mw * 64 + m * 16 + hi * 4 + r], s);
        }
    }
}

// ---------------------------------------------------------------------------
// Per-batch softmax over T + pooling -> features[b][512]
// ---------------------------------------------------------------------------
__global__ __launch_bounds__(256) void attn_pool(
    const float* __restrict__ scores, const unsigned short* __restrict__ hb,
    float* __restrict__ features)
{
    int b = blockIdx.x;
    int tid = threadIdx.x;
    __shared__ float w[T_SZ];
    __shared__ float smax[4], ssum[4];

    float sc = (tid < T_SZ) ? scores[(size_t)tid * B_SZ + b] : -INFINITY;
    float m = sc;
    for (int o = 32; o; o >>= 1) m = fmaxf(m, __shfl_xor(m, o));
    if ((tid & 63) == 0) smax[tid >> 6] = m;
    __syncthreads();
    float M = fmaxf(fmaxf(smax[0], smax[1]), fmaxf(smax[2], smax[3]));
    float e = (tid < T_SZ) ? expf(sc - M) : 0.f;
    float se = e;
    for (int o = 32; o; o >>= 1) se += __shfl_xor(se, o);
    if ((tid & 63) == 0) ssum[tid >> 6] = se;
    __syncthreads();
    float S = ssum[0] + ssum[1] + ssum[2] + ssum[3];
    if (tid < T_SZ) w[tid] = e / S;
    __syncthreads();

    for (int e0 = tid; e0 < E_SZ; e0 += 256) {
        float acc = 0.f;
        for (int t = 0; t < T_SZ; ++t)
            acc += w[t] * bf2f(hb[((size_t)t * B_SZ + b) * E_SZ + e0]);
        features[(size_t)b * E_SZ + e0] = acc;
    }
}

// ---------------------------------------------------------------------------
// FC: 64 blocks x 8 batch rows
// ---------------------------------------------------------------------------
__global__ __launch_bounds__(256) void fc_kernel(
    const float* __restrict__ features, const float* __restrict__ fc_w,
    const float* __restrict__ fc_b, float* __restrict__ logits)
{
    int bb = blockIdx.x * 8;
    int tid = threadIdx.x;
    __shared__ float f[8][E_SZ];
    for (int i = tid; i < 8 * E_SZ; i += 256)
        f[i >> 9][i & 511] = features[(size_t)(bb + (i >> 9)) * E_SZ + (i & 511)];
    __syncthreads();
    for (int o = tid; o < K_SZ * L_SZ; o += 256) {
        const float* wr = fc_w + (size_t)o * E_SZ;
        float acc[8];
        float bv = fc_b[o];
        #pragma unroll
        for (int b = 0; b < 8; ++b) acc[b] = bv;
        for (int e0 = 0; e0 < E_SZ; ++e0) {
            float wv = wr[e0];
            #pragma unroll
            for (int b = 0; b < 8; ++b) acc[b] += f[b][e0] * wv;
        }
        #pragma unroll
        for (int b = 0; b < 8; ++b)
            logits[(size_t)(bb + b) * (K_SZ * L_SZ) + o] = acc[b];
    }
}

// ---------------------------------------------------------------------------
// CRF loss per batch element
// ---------------------------------------------------------------------------
__global__ __launch_bounds__(64) void crf_kernel(
    const float* __restrict__ logits, const int* __restrict__ labels,
    const float* __restrict__ start_t, const float* __restrict__ trans,
    const float* __restrict__ end_t, float* __restrict__ per_loss)
{
    int b = blockIdx.x;
    int tid = threadIdx.x;
    __shared__ float tr[K_SZ * K_SZ];
    __shared__ float em[K_SZ * L_SZ];
    __shared__ float alpha[K_SZ];

    for (int i = tid; i < K_SZ * K_SZ; i += 64) tr[i] = trans[i];
    for (int i = tid; i < K_SZ * L_SZ; i += 64)
        em[i] = logits[(size_t)b * (K_SZ * L_SZ) + i];
    __syncthreads();
    if (tid < K_SZ) alpha[tid] = start_t[tid] + em[tid];
    __syncthreads();

    for (int t = 1; t < L_SZ; ++t) {
        float na = 0.f;
        if (tid < K_SZ) {
            float m = -INFINITY;
            for (int k = 0; k < K_SZ; ++k)
                m = fmaxf(m, alpha[k] + tr[k * K_SZ + tid]);
            float s = 0.f;
            for (int k = 0; k < K_SZ; ++k)
                s += expf(alpha[k] + tr[k * K_SZ + tid] - m);
            na = m + logf(s) + em[t * K_SZ + tid];
        }
        __syncthreads();
        if (tid < K_SZ) alpha[tid] = na;
        __syncthreads();
    }

    float v = (tid < K_SZ) ? alpha[tid] + end_t[tid] : -INFINITY;
    float m = v;
    for (int o = 32; o; o >>= 1) m = fmaxf(m, __shfl_xor(m, o));
    float e = (tid < K_SZ) ? expf(v - m) : 0.f;
    for (int o = 32; o; o >>= 1) e += __shfl_xor(e, o);
    float logZ = m + logf(e);

    if (tid == 0) {
        const int* lab = labels + (size_t)b * L_SZ;
        float score = start_t[lab[0]] + end_t[lab[L_SZ - 1]];
        for (int t = 0; t < L_SZ; ++t) score += em[t * K_SZ + lab[t]];
        for (int t = 0; t < L_SZ - 1; ++t) score += tr[lab[t] * K_SZ + lab[t + 1]];
        per_loss[b] = logZ - score;
    }
}

__global__ __launch_bounds__(256) void reduce_kernel(
    const float* __restrict__ per_loss, float* __restrict__ out)
{
    int tid = threadIdx.x;
    float s = per_loss[tid] + per_loss[tid + 256];
    for (int o = 32; o; o >>= 1) s += __shfl_xor(s, o);
    __shared__ float part[4];
    if ((tid & 63) == 0) part[tid >> 6] = s;
    __syncthreads();
    if (tid == 0) out[0] = (part[0] + part[1] + part[2] + part[3]) / (float)B_SZ;
}

// ---------------------------------------------------------------------------
extern "C" void kernel_launch(void* const* d_in, const int* in_sizes, int n_in,
                              void* d_out, int out_size, void* d_ws, size_t ws_size,
                              hipStream_t stream)
{
    const float* x      = (const float*)d_in[0];
    const int*   labels = (const int*)d_in[1];
    const float* w_ih_f = (const float*)d_in[2];
    const float* w_hh_f = (const float*)d_in[3];
    const float* b_f    = (const float*)d_in[4];
    const float* w_ih_b = (const float*)d_in[5];
    const float* w_hh_b = (const float*)d_in[6];
    const float* b_b    = (const float*)d_in[7];
    const float* aw1    = (const float*)d_in[8];
    const float* ab1    = (const float*)d_in[9];
    const float* aw2    = (const float*)d_in[10];
    // d_in[11] = ab2 : softmax-invariant, unused
    const float* fc_w   = (const float*)d_in[12];
    const float* fc_b   = (const float*)d_in[13];
    const float* start_t = (const float*)d_in[14];
    const float* trans   = (const float*)d_in[15];
    const float* end_t   = (const float*)d_in[16];
    float* out = (float*)d_out;

    char* ws = (char*)d_ws;
    size_t off = 0;
    unsigned char* Wt  = (unsigned char*)(ws + off); off += (size_t)524288;             // w_hh fp8 frags
    unsigned char* Wp  = (unsigned char*)(ws + off); off += (size_t)2048 * 128;         // w_ih fp8
    float* biasp       = (float*)(ws + off);         off += (size_t)2048 * 4;
    short* aw1b        = (short*)(ws + off);         off += (size_t)H_SZ * E_SZ * 2;
    unsigned char* xb  = (unsigned char*)(ws + off); off += (size_t)B_SZ * T_SZ * D_SZ; // 8.4MB fp8
    unsigned char* xp  = (unsigned char*)(ws + off); off += (size_t)T_SZ * B_SZ * 2048; // 134MB fp8
    unsigned short* hb = (unsigned short*)(ws + off); off += (size_t)T_SZ * B_SZ * E_SZ * 2; // 67MB
    float* scores      = (float*)(ws + off);         off += (size_t)T_SZ * B_SZ * 4;
    float* features    = (float*)(ws + off);         off += (size_t)B_SZ * E_SZ * 4;
    float* logits      = (float*)(ws + off);         off += (size_t)B_SZ * K_SZ * L_SZ * 4;
    float* per_loss    = (float*)(ws + off);         off += (size_t)B_SZ * 4;

    // 1. weight/bias/x prep
    prep_whh<<<2048, 256, 0, stream>>>(w_hh_f, w_hh_b, Wt);
    prep_wih<<<1024, 256, 0, stream>>>(w_ih_f, b_f, w_ih_b, b_b, Wp, biasp);
    prep_aw<<<(H_SZ * E_SZ + 255) / 256, 256, 0, stream>>>(aw1, aw1b);
    xprep<<<(B_SZ * T_SZ * D_SZ / 4 + 255) / 256, 256, 0, stream>>>(x, xb);

    // 2. zero score accumulator
    hipMemsetAsync(scores, 0, (size_t)T_SZ * B_SZ * 4, stream);

    // 3. x-projection for all timesteps (256 CUs, fp8 MFMA)
    xproj_gemm<<<8192, 256, 0, stream>>>(xb, Wp, biasp, xp);

    // 4. BiLSTM recurrence (K=256 only), weights VGPR-resident
    recur_kernel<<<64, 1024, 0, stream>>>(xp, Wt, hb);

    // 5. attention MLP scores (bf16 MFMA)
    attn_mfma<<<1024, 256, 0, stream>>>(hb, aw1b, ab1, aw2, scores);

    // 6. softmax + pooling
    attn_pool<<<B_SZ, 256, 0, stream>>>(scores, hb, features);

    // 7. FC to emissions
    fc_kernel<<<64, 256, 0, stream>>>(features, fc_w, fc_b, logits);

    // 8. CRF loss
    crf_kernel<<<B_SZ, 64, 0, stream>>>(logits, labels, start_t, trans, end_t, per_loss);

    // 9. mean
    reduce_kernel<<<1, 256, 0, stream>>>(per_loss, out);
}